// Round 1
// baseline (160.428 us; speedup 1.0000x reference)
//
#include <hip/hip_runtime.h>
#include <hip/hip_bf16.h>

// relu(x[n,k,:] @ W + b) max-pooled over k.
// x: [100000, 32, 64] f32, W: [64, 64] f32 (stored [n_in][n_out]), b: [64] f32
// out: [100000, 64] f32
//
// One wave per node. bf16 MFMA (16x16x32), W held in registers as B-fragments,
// x loaded global->reg (coalesced dwordx4) and converted to bf16 in-register.
// Memory-bound: 845 MB HBM traffic, ~134 us floor at 6.3 TB/s.

typedef __attribute__((ext_vector_type(8))) short bf16x8;
typedef __attribute__((ext_vector_type(4))) float f32x4;

#define KNEIGH 32
#define NIN 64
#define NOUT 64

// fp32 -> bf16 bits, round-to-nearest-even (inputs are finite normals)
__device__ __forceinline__ short f2bf(float f) {
    unsigned u = __builtin_bit_cast(unsigned, f);
    unsigned r = (u + 0x7fffu + ((u >> 16) & 1u)) >> 16;
    return (short)r;
}

__global__ __launch_bounds__(256) void edge_mfma_kernel(
    const float* __restrict__ x, const float* __restrict__ W,
    const float* __restrict__ b, float* __restrict__ out,
    int n_nodes, int wave_stride)
{
    const int lane = threadIdx.x & 63;
    const int l16  = lane & 15;   // col within 16-wide tile / row within A M-tile
    const int lg   = lane >> 4;   // lane group 0..3

    // ---- per-wave constants: W as 8 B-fragments (4 N-tiles x 2 K-steps), bias ----
    // B layout for 16x16x32: col n = lane&15, k = (lane>>4)*8 + j
    bf16x8 Wf[4][2];
#pragma unroll
    for (int t = 0; t < 4; ++t) {
#pragma unroll
        for (int s = 0; s < 2; ++s) {
#pragma unroll
            for (int j = 0; j < 8; ++j) {
                int k = s * 32 + lg * 8 + j;   // n_in index
                int o = t * 16 + l16;          // n_out index
                Wf[t][s][j] = f2bf(W[k * NOUT + o]);
            }
        }
    }
    float bias[4];
#pragma unroll
    for (int t = 0; t < 4; ++t) bias[t] = b[t * 16 + l16];

    const int wave = blockIdx.x * (blockDim.x >> 6) + (threadIdx.x >> 6);

    for (int n = wave; n < n_nodes; n += wave_stride) {
        const float* xb = x + (size_t)n * (KNEIGH * NIN);

        // ---- load x fragments: A layout row m = lane&15, k = (lane>>4)*8 + j ----
        // lane reads 8 contiguous floats per (m-tile, k-step): 2x dwordx4
        f32x4 xr[2][2][2];
#pragma unroll
        for (int m = 0; m < 2; ++m) {
#pragma unroll
            for (int s = 0; s < 2; ++s) {
                const f32x4* p = reinterpret_cast<const f32x4*>(
                    xb + (m * 16 + l16) * NIN + s * 32 + lg * 8);
                xr[m][s][0] = p[0];
                xr[m][s][1] = p[1];
            }
        }

        // ---- convert to bf16 A-fragments ----
        bf16x8 Af[2][2];
#pragma unroll
        for (int m = 0; m < 2; ++m) {
#pragma unroll
            for (int s = 0; s < 2; ++s) {
#pragma unroll
                for (int j = 0; j < 4; ++j) {
                    Af[m][s][j]     = f2bf(xr[m][s][0][j]);
                    Af[m][s][4 + j] = f2bf(xr[m][s][1][j]);
                }
            }
        }

        // ---- 16 MFMAs: acc[m][t] over 2 K-steps ----
        f32x4 acc[2][4];
#pragma unroll
        for (int m = 0; m < 2; ++m)
#pragma unroll
            for (int t = 0; t < 4; ++t)
                acc[m][t] = (f32x4){0.f, 0.f, 0.f, 0.f};

#pragma unroll
        for (int m = 0; m < 2; ++m) {
#pragma unroll
            for (int t = 0; t < 4; ++t) {
                acc[m][t] = __builtin_amdgcn_mfma_f32_16x16x32_bf16(
                    Af[m][0], Wf[t][0], acc[m][t], 0, 0, 0);
                acc[m][t] = __builtin_amdgcn_mfma_f32_16x16x32_bf16(
                    Af[m][1], Wf[t][1], acc[m][t], 0, 0, 0);
            }
        }

        // ---- epilogue: max over 32 rows per column, then relu(max + bias) ----
        // C/D layout: col = lane&15, row = (lane>>4)*4 + reg (+16 for m-tile 1)
        float res[4];
#pragma unroll
        for (int t = 0; t < 4; ++t) {
            float v0 = fmaxf(acc[0][t][0], acc[1][t][0]);
            float v1 = fmaxf(acc[0][t][1], acc[1][t][1]);
            float v2 = fmaxf(acc[0][t][2], acc[1][t][2]);
            float v3 = fmaxf(acc[0][t][3], acc[1][t][3]);
            float r = fmaxf(fmaxf(v0, v1), fmaxf(v2, v3));
            // combine the 4 lane-groups (disjoint row sets)
            r = fmaxf(r, __shfl_xor(r, 16));
            r = fmaxf(r, __shfl_xor(r, 32));
            res[t] = fmaxf(r + bias[t], 0.0f);
        }

        // lane lg*16+l16 writes column lg*16+l16: select res[lg] -> coalesced store
        float val = (lg == 0) ? res[0] : (lg == 1) ? res[1] : (lg == 2) ? res[2] : res[3];
        out[(size_t)n * NOUT + lane] = val;
    }
}

extern "C" void kernel_launch(void* const* d_in, const int* in_sizes, int n_in,
                              void* d_out, int out_size, void* d_ws, size_t ws_size,
                              hipStream_t stream) {
    const float* x = (const float*)d_in[0];
    const float* W = (const float*)d_in[1];
    const float* b = (const float*)d_in[2];
    float* out = (float*)d_out;

    const int n_nodes = in_sizes[0] / (KNEIGH * NIN);  // 100000
    const int blocks = 2048;                           // grid-stride, 4 waves/block
    const int wave_stride = blocks * 4;

    hipLaunchKernelGGL(edge_mfma_kernel, dim3(blocks), dim3(256), 0, stream,
                       x, W, b, out, n_nodes, wave_stride);
}